// Round 4
// baseline (364.380 us; speedup 1.0000x reference)
//
#include <hip/hip_runtime.h>
#include <hip/hip_bf16.h>
#include <stdint.h>

#define GSIZE 64
#define MDIM 4096
#define KDIM 4096
#define NDIM 4096
#define RANK 32
#define KE   4160   // K + 32 (lora) + 32 (zero pad) -> 65 * 64
#define NG   64     // K / GSIZE
#define NSPLIT 8    // split-K factor for lora-down GEMM

// fused-prep role boundaries (block index)
#define B_WPREP (65 * 64)               // [0, 4160)       w tiles (65 kt x 64 nb)
#define B_LORAT (B_WPREP + 32 * NSPLIT) // [4160, 4416)    lora+quant (32 mb x 8 sp)

typedef __bf16 bf16x4 __attribute__((ext_vector_type(4)));
typedef __bf16 bf16x8 __attribute__((ext_vector_type(8)));
typedef float  f32x4  __attribute__((ext_vector_type(4)));

#define GPTR(p) ((__attribute__((address_space(1))) void*)(uintptr_t)(p))
#define LPTR(p) ((__attribute__((address_space(3))) void*)(p))

// ---------------------------------------------------------------------------
// Fused prep kernel, two roles by blockIdx.x:
//  role WPREP: dequant int4 W + transpose -> Wt[n][k] (tail tile = lora_up)
//  role LORAT: t_partial = x @ lora_down (MFMA, split-K)  AND  per-group int4
//              quant/dequant of x -> A (quant rides on the staged x values;
//              a block covers rows m0..m0+128, k in [sp*512,(sp+1)*512) = 8
//              full 64-groups per row, so coverage of A[:,0:4096] is exact).
// ---------------------------------------------------------------------------
__global__ __launch_bounds__(256) void k_prep(const float* __restrict__ x,
                                              const int*   __restrict__ qw,
                                              const float* __restrict__ wsc,
                                              const float* __restrict__ ld,
                                              const float* __restrict__ lu,
                                              const float* __restrict__ smooth,
                                              __bf16* __restrict__ A,
                                              __bf16* __restrict__ Wt,
                                              float* __restrict__ tws) {
    __shared__ __attribute__((aligned(16))) char smem[10240];
    int b   = blockIdx.x;
    int tid = threadIdx.x;

    if (b < B_WPREP) {
        // ---------------- WPREP role: one 64x64 tile ----------------
        __bf16 (*tile)[68] = (__bf16(*)[68])smem;   // +4 pad
        int n0 = (b & 63) * 64;
        int kt = b >> 6;                  // 0..64
        int k0 = kt * 64;
        int tr = tid >> 4;                // 0..15
        int tc = (tid & 15) * 4;          // 0,4,...,60
        if (kt < NG) {
            float4 ws = *(const float4*)(wsc + (size_t)kt * NDIM + n0 + tc);
            #pragma unroll
            for (int r = tr; r < 64; r += 16) {
                int4 q = *(const int4*)(qw + (size_t)(k0 + r) * NDIM + n0 + tc);
                tile[r][tc + 0] = (__bf16)((float)q.x * ws.x);
                tile[r][tc + 1] = (__bf16)((float)q.y * ws.y);
                tile[r][tc + 2] = (__bf16)((float)q.z * ws.z);
                tile[r][tc + 3] = (__bf16)((float)q.w * ws.w);
            }
        } else {
            #pragma unroll
            for (int r = tr; r < 64; r += 16) {
                if (r < RANK) {
                    float4 lv = *(const float4*)(lu + (size_t)r * NDIM + n0 + tc);
                    tile[r][tc + 0] = (__bf16)lv.x;
                    tile[r][tc + 1] = (__bf16)lv.y;
                    tile[r][tc + 2] = (__bf16)lv.z;
                    tile[r][tc + 3] = (__bf16)lv.w;
                } else {
                    tile[r][tc + 0] = (__bf16)0.f;
                    tile[r][tc + 1] = (__bf16)0.f;
                    tile[r][tc + 2] = (__bf16)0.f;
                    tile[r][tc + 3] = (__bf16)0.f;
                }
            }
        }
        __syncthreads();
        int nn = tid >> 3;            // 0..31
        int ks = (tid & 7) * 8;       // 0..56
        #pragma unroll
        for (int p = 0; p < 2; ++p) {
            int n = nn + p * 32;
            bf16x8 v;
            #pragma unroll
            for (int e = 0; e < 8; ++e) v[e] = tile[ks + e][n];
            *(bf16x8*)(Wt + (size_t)(n0 + n) * KE + k0 + ks) = v;
        }
        return;
    }

    // ------------- LORAT + QUANT role: 128 rows x 512 k -------------
    {
        __bf16* AsL = (__bf16*)smem;            // [128][32], xor-swizzled
        __bf16* BsL = (__bf16*)(smem + 8192);   // [32 n][32 k]
        int idx   = b - B_WPREP;
        int m0    = (idx & 31) * 128;
        int sp    = idx >> 5;                   // 0..7
        int kbase = sp * 512;
        int lane = tid & 63;
        int wave = tid >> 6;
        int quad = lane >> 4;
        int mrow = lane & 15;

        // per-it (it=0: row tid>>2, it=1: row 64+(tid>>2)) constants
        int rr[2], gg[2];
        #pragma unroll
        for (int it = 0; it < 2; ++it) {
            int slot = it * 256 + tid;
            rr[it] = slot >> 2;                  // row 0..127
            gg[it] = (slot & 3) ^ (rr[it] & 3);  // swizzled 16B group
        }

        f32x4 z = {0.f, 0.f, 0.f, 0.f};
        f32x4 acc[2][2];
        acc[0][0] = z; acc[0][1] = z; acc[1][0] = z; acc[1][1] = z;

        float he[2][8];   // smoothed x, even substep
        float ho[2][8];   // smoothed x, odd substep
        float am[2];      // running group absmax per it

        for (int dstep = 0; dstep < 8; ++dstep) {
            #pragma unroll
            for (int s2 = 0; s2 < 2; ++s2) {
                int kk = kbase + (dstep * 2 + s2) * 32;
                // ---- stage x -> bf16 LDS; keep smoothed copy in regs ----
                #pragma unroll
                for (int it = 0; it < 2; ++it) {
                    int r = rr[it], g = gg[it];
                    const float* src = x + (size_t)(m0 + r) * KDIM + kk + g * 8;
                    float4 a0 = *(const float4*)src;
                    float4 a1 = *(const float4*)(src + 4);
                    const float* sms = smooth + kk + g * 8;
                    float4 s0 = *(const float4*)sms;
                    float4 s1 = *(const float4*)(sms + 4);
                    bf16x8 v = {(__bf16)a0.x, (__bf16)a0.y, (__bf16)a0.z, (__bf16)a0.w,
                                (__bf16)a1.x, (__bf16)a1.y, (__bf16)a1.z, (__bf16)a1.w};
                    *(bf16x8*)(AsL + (it * 256 + tid) * 8) = v;
                    float* h = s2 ? ho[it] : he[it];
                    h[0] = a0.x * __builtin_amdgcn_rcpf(s0.x);
                    h[1] = a0.y * __builtin_amdgcn_rcpf(s0.y);
                    h[2] = a0.z * __builtin_amdgcn_rcpf(s0.z);
                    h[3] = a0.w * __builtin_amdgcn_rcpf(s0.w);
                    h[4] = a1.x * __builtin_amdgcn_rcpf(s1.x);
                    h[5] = a1.y * __builtin_amdgcn_rcpf(s1.y);
                    h[6] = a1.z * __builtin_amdgcn_rcpf(s1.z);
                    h[7] = a1.w * __builtin_amdgcn_rcpf(s1.w);
                    float a = fmaxf(fmaxf(fmaxf(fabsf(h[0]), fabsf(h[1])),
                                          fmaxf(fabsf(h[2]), fabsf(h[3]))),
                                    fmaxf(fmaxf(fabsf(h[4]), fabsf(h[5])),
                                          fmaxf(fabsf(h[6]), fabsf(h[7]))));
                    am[it] = s2 ? fmaxf(am[it], a) : a;
                }
                // ---- stage lora_down chunk [k 32][n 32] -> [n][k] ----
                #pragma unroll
                for (int i2 = 0; i2 < 4; ++i2) {
                    int j = i2 * 256 + tid;
                    int r = j >> 5, n = j & 31;
                    BsL[n * 32 + r] = (__bf16)ld[(size_t)(kk + r) * RANK + n];
                }
                __syncthreads();
                bf16x8 av[2], bv[2];
                #pragma unroll
                for (int i = 0; i < 2; ++i) {
                    int row  = wave * 32 + i * 16 + mrow;
                    int slot = row * 4 + (quad ^ (row & 3));
                    av[i] = *(const bf16x8*)(AsL + slot * 8);
                }
                #pragma unroll
                for (int j = 0; j < 2; ++j)
                    bv[j] = *(const bf16x8*)(BsL + (j * 16 + mrow) * 32 + quad * 8);
                #pragma unroll
                for (int i = 0; i < 2; ++i)
                    #pragma unroll
                    for (int j = 0; j < 2; ++j)
                        acc[i][j] = __builtin_amdgcn_mfma_f32_16x16x32_bf16(av[i], bv[j], acc[i][j], 0, 0, 0);
                __syncthreads();
            }
            // ---- quantize the completed 64-group (2 substeps) -> A ----
            int kk0 = kbase + dstep * 64;
            #pragma unroll
            for (int it = 0; it < 2; ++it) {
                float a = am[it];
                // 4 threads (lanes 4r..4r+3) hold one row's 32-k per substep
                a = fmaxf(a, __shfl_xor(a, 1, 64));
                a = fmaxf(a, __shfl_xor(a, 2, 64));
                float ascale = fmaxf(a * (1.0f / 7.0f), 1e-8f);
                float rin = __builtin_amdgcn_rcpf(ascale);
                bf16x8 qe, qo;
                #pragma unroll
                for (int j = 0; j < 8; ++j) {
                    float q0 = fminf(fmaxf(rintf(he[it][j] * rin), -8.f), 7.f);
                    float q1 = fminf(fmaxf(rintf(ho[it][j] * rin), -8.f), 7.f);
                    qe[j] = (__bf16)(q0 * ascale);
                    qo[j] = (__bf16)(q1 * ascale);
                }
                int r = rr[it], g = gg[it];
                __bf16* arow = A + (size_t)(m0 + r) * KE;
                *(bf16x8*)(arow + kk0 + g * 8)      = qe;
                *(bf16x8*)(arow + kk0 + 32 + g * 8) = qo;
            }
        }
        float* tout = tws + (size_t)sp * MDIM * RANK;
        #pragma unroll
        for (int i = 0; i < 2; ++i)
            #pragma unroll
            for (int j = 0; j < 2; ++j)
                #pragma unroll
                for (int r = 0; r < 4; ++r) {
                    int rowg = m0 + wave * 32 + i * 16 + quad * 4 + r;
                    int col  = j * 16 + mrow;
                    tout[(size_t)rowg * RANK + col] = acc[i][j][r];
                }
    }
}

// ---------------------------------------------------------------------------
// Reduce split-K partials, write t (bf16) + zero pad into A cols [4096, 4160)
// ---------------------------------------------------------------------------
__global__ __launch_bounds__(256) void k_fin(const float* __restrict__ tws,
                                             __bf16* __restrict__ A) {
    int idx = blockIdx.x * 256 + threadIdx.x;
    int m = idx >> 4, cq = idx & 15;
    int c = cq * 4;
    bf16x4 v = {(__bf16)0.f, (__bf16)0.f, (__bf16)0.f, (__bf16)0.f};
    if (c < RANK) {
        f32x4 s = {0.f, 0.f, 0.f, 0.f};
        #pragma unroll
        for (int sp = 0; sp < NSPLIT; ++sp) {
            f32x4 p = *(const f32x4*)(tws + ((size_t)sp * MDIM + m) * RANK + c);
            s.x += p.x; s.y += p.y; s.z += p.z; s.w += p.w;
        }
        v[0] = (__bf16)s.x; v[1] = (__bf16)s.y; v[2] = (__bf16)s.z; v[3] = (__bf16)s.w;
    }
    *(bf16x4*)(A + (size_t)m * KE + KDIM + c) = v;
}

// ---------------------------------------------------------------------------
// Main GEMM (m97 structure + XOR swizzle) — frozen control since round 2.
// ---------------------------------------------------------------------------
__global__ __launch_bounds__(256) void k_gemm(const __bf16* __restrict__ A,
                                              const __bf16* __restrict__ Wt,
                                              const float*  __restrict__ bias,
                                              float* __restrict__ out) {
    __shared__ __attribute__((aligned(16))) __bf16 As[128 * 64];
    __shared__ __attribute__((aligned(16))) __bf16 Bs[128 * 64];
    int tid  = threadIdx.x;
    int lane = tid & 63;
    int wave = tid >> 6;
    int quad = lane >> 4;
    int mrow = lane & 15;
    int wm = wave >> 1, wn = wave & 1;
    int m0 = blockIdx.y * 128, n0 = blockIdx.x * 128;

    f32x4 z = {0.f, 0.f, 0.f, 0.f};
    f32x4 acc[4][4];
    #pragma unroll
    for (int i = 0; i < 4; ++i)
        #pragma unroll
        for (int j = 0; j < 4; ++j) acc[i][j] = z;

    const __bf16* Ab = A  + (size_t)m0 * KE;
    const __bf16* Bb = Wt + (size_t)n0 * KE;

    for (int kt = 0; kt < KE / 64; ++kt) {
        int k0 = kt * 64;
        #pragma unroll
        for (int it = 0; it < 4; ++it) {
            int c = it * 256 + tid;       // 16B-slot index 0..1023
            int r = c >> 3;               // tile row 0..127
            int g = (c & 7) ^ (r & 7);    // swizzled col group
            int ldsoff = (it * 256 + wave * 64) * 16;  // wave-uniform base
            __builtin_amdgcn_global_load_lds(GPTR(Ab + (size_t)r * KE + k0 + g * 8),
                                             LPTR((char*)As + ldsoff), 16, 0, 0);
            __builtin_amdgcn_global_load_lds(GPTR(Bb + (size_t)r * KE + k0 + g * 8),
                                             LPTR((char*)Bs + ldsoff), 16, 0, 0);
        }
        __syncthreads();
        #pragma unroll
        for (int s = 0; s < 2; ++s) {
            bf16x8 av[4], bv[4];
            #pragma unroll
            for (int i = 0; i < 4; ++i) {
                int row  = wm * 64 + i * 16 + mrow;
                int slot = row * 8 + ((s * 4 + quad) ^ (row & 7));
                av[i] = *(const bf16x8*)(As + slot * 8);
            }
            #pragma unroll
            for (int j = 0; j < 4; ++j) {
                int row  = wn * 64 + j * 16 + mrow;
                int slot = row * 8 + ((s * 4 + quad) ^ (row & 7));
                bv[j] = *(const bf16x8*)(Bs + slot * 8);
            }
            #pragma unroll
            for (int i = 0; i < 4; ++i)
                #pragma unroll
                for (int j = 0; j < 4; ++j)
                    acc[i][j] = __builtin_amdgcn_mfma_f32_16x16x32_bf16(av[i], bv[j], acc[i][j], 0, 0, 0);
        }
        __syncthreads();
    }

    // epilogue: C/D layout col = lane&15, row = quad*4 + reg (m89/m91)
    #pragma unroll
    for (int j = 0; j < 4; ++j) {
        int col = n0 + wn * 64 + j * 16 + mrow;
        float bvs = bias[col];
        #pragma unroll
        for (int i = 0; i < 4; ++i) {
            int rbase = m0 + wm * 64 + i * 16 + quad * 4;
            #pragma unroll
            for (int r = 0; r < 4; ++r)
                out[(size_t)(rbase + r) * NDIM + col] = acc[i][j][r] + bvs;
        }
    }
}

extern "C" void kernel_launch(void* const* d_in, const int* in_sizes, int n_in,
                              void* d_out, int out_size, void* d_ws, size_t ws_size,
                              hipStream_t stream) {
    const float* x    = (const float*)d_in[0];
    const int*   qw   = (const int*)  d_in[1];
    const float* wsc  = (const float*)d_in[2];
    const float* ld   = (const float*)d_in[3];
    const float* lu   = (const float*)d_in[4];
    const float* sm   = (const float*)d_in[5];
    const float* bias = (const float*)d_in[6];
    float* out = (float*)d_out;

    char* ws = (char*)d_ws;
    __bf16* A   = (__bf16*)ws;                                   // M*KE bf16
    __bf16* Wt  = (__bf16*)(ws + (size_t)MDIM * KE * 2);         // N*KE bf16
    float*  tws = (float*) (ws + (size_t)MDIM * KE * 4);         // NSPLIT*M*RANK f32

    k_prep<<<B_LORAT, 256, 0, stream>>>(x, qw, wsc, ld, lu, sm, A, Wt, tws);
    k_fin<<<(MDIM * 16) / 256, 256, 0, stream>>>(tws, A);
    k_gemm<<<dim3(NDIM / 128, MDIM / 128), 256, 0, stream>>>(A, Wt, bias, out);
}

// Round 5
// 337.321 us; speedup vs baseline: 1.0802x; 1.0802x over previous
//
#include <hip/hip_runtime.h>
#include <hip/hip_bf16.h>
#include <stdint.h>

#define GSIZE 64
#define MDIM 4096
#define KDIM 4096
#define NDIM 4096
#define RANK 32
#define KE   4160   // K + 32 (lora) + 32 (zero pad) -> 65 * 64
#define NG   64     // K / GSIZE
#define NSPLIT 8    // split-K factor for lora-down GEMM

// fused-prep role boundaries (block index) — LORAT first so the
// latency-bound role overlaps the BW-bound roles instead of tailing them.
#define N_LORAT (32 * NSPLIT)           // 256
#define B_WPREP0 N_LORAT                // 256
#define N_WPREP (65 * 64)               // 4160
#define B_QUANT0 (B_WPREP0 + N_WPREP)   // 4416
#define NBLOCKS  (B_QUANT0 + MDIM)      // 8512

typedef __bf16 bf16x4 __attribute__((ext_vector_type(4)));
typedef __bf16 bf16x8 __attribute__((ext_vector_type(8)));
typedef float  f32x4  __attribute__((ext_vector_type(4)));

#define GPTR(p) ((__attribute__((address_space(1))) void*)(uintptr_t)(p))
#define LPTR(p) ((__attribute__((address_space(3))) void*)(p))

// ---------------------------------------------------------------------------
// Fused prep kernel: three independent roles selected by blockIdx.x.
//  role LORAT: t_partial = x @ lora_down (MFMA, split-K, per-split outputs)
//  role WPREP: dequant int4 W + transpose -> Wt[n][k] (tail tile = lora_up)
//  role QUANT: smooth + per-group int4 quant/dequant of x -> A[m][0..4096)
// ---------------------------------------------------------------------------
__global__ __launch_bounds__(256) void k_prep(const float* __restrict__ x,
                                              const int*   __restrict__ qw,
                                              const float* __restrict__ wsc,
                                              const float* __restrict__ ld,
                                              const float* __restrict__ lu,
                                              const float* __restrict__ smooth,
                                              __bf16* __restrict__ A,
                                              __bf16* __restrict__ Wt,
                                              float* __restrict__ tws) {
    __shared__ __attribute__((aligned(16))) char smem[10240];
    int b   = blockIdx.x;
    int tid = threadIdx.x;

    if (b < N_LORAT) {
        // ------------- LORAT role: 128 rows x 32 cols, K-chunk 512 ---------
        __bf16* AsL = (__bf16*)smem;            // [128][32], xor-swizzled
        __bf16* BsL = (__bf16*)(smem + 8192);   // [32 n][32 k]
        int m0    = (b & 31) * 128;
        int sp    = b >> 5;                     // 0..7
        int kbase = sp * 512;
        int lane = tid & 63;
        int wave = tid >> 6;
        int quad = lane >> 4;
        int mrow = lane & 15;

        f32x4 z = {0.f, 0.f, 0.f, 0.f};
        f32x4 acc[2][2];
        acc[0][0] = z; acc[0][1] = z; acc[1][0] = z; acc[1][1] = z;

        for (int step = 0; step < 16; ++step) {
            int kk = kbase + step * 32;
            // A staging: fp32 load + convert; linear slots (conflict-free
            // writes), content xor-swizzled within the row's 4 16B-groups.
            #pragma unroll
            for (int it = 0; it < 2; ++it) {
                int slot = it * 256 + tid;       // 0..511
                int r = slot >> 2;               // row 0..127
                int g = (slot & 3) ^ (r & 3);    // swizzled 16B group
                const float* src = x + (size_t)(m0 + r) * KDIM + kk + g * 8;
                float4 a0 = *(const float4*)src;
                float4 a1 = *(const float4*)(src + 4);
                bf16x8 v = {(__bf16)a0.x, (__bf16)a0.y, (__bf16)a0.z, (__bf16)a0.w,
                            (__bf16)a1.x, (__bf16)a1.y, (__bf16)a1.z, (__bf16)a1.w};
                *(bf16x8*)(AsL + slot * 8) = v;
            }
            // B staging: ld chunk 32k x 32n, transposed to [n][k]
            #pragma unroll
            for (int i2 = 0; i2 < 4; ++i2) {
                int j = i2 * 256 + tid;
                int r = j >> 5, n = j & 31;
                BsL[n * 32 + r] = (__bf16)ld[(size_t)(kk + r) * RANK + n];
            }
            __syncthreads();
            bf16x8 av[2], bv[2];
            #pragma unroll
            for (int i = 0; i < 2; ++i) {
                int row  = wave * 32 + i * 16 + mrow;
                int slot = row * 4 + (quad ^ (row & 3));
                av[i] = *(const bf16x8*)(AsL + slot * 8);
            }
            #pragma unroll
            for (int j = 0; j < 2; ++j)
                bv[j] = *(const bf16x8*)(BsL + (j * 16 + mrow) * 32 + quad * 8);
            #pragma unroll
            for (int i = 0; i < 2; ++i)
                #pragma unroll
                for (int j = 0; j < 2; ++j)
                    acc[i][j] = __builtin_amdgcn_mfma_f32_16x16x32_bf16(av[i], bv[j], acc[i][j], 0, 0, 0);
            __syncthreads();
        }
        float* tout = tws + (size_t)sp * MDIM * RANK;
        #pragma unroll
        for (int i = 0; i < 2; ++i)
            #pragma unroll
            for (int j = 0; j < 2; ++j)
                #pragma unroll
                for (int r = 0; r < 4; ++r) {
                    int rowg = m0 + wave * 32 + i * 16 + quad * 4 + r;
                    int col  = j * 16 + mrow;
                    tout[(size_t)rowg * RANK + col] = acc[i][j][r];
                }
        return;
    }

    if (b < B_QUANT0) {
        // ---------------- WPREP role: one 64x64 tile ----------------
        __bf16 (*tile)[68] = (__bf16(*)[68])smem;   // +4 pad
        int idx = b - B_WPREP0;
        int n0 = (idx & 63) * 64;
        int kt = idx >> 6;                // 0..64
        int k0 = kt * 64;
        int tr = tid >> 4;                // 0..15
        int tc = (tid & 15) * 4;          // 0,4,...,60
        if (kt < NG) {
            float4 ws = *(const float4*)(wsc + (size_t)kt * NDIM + n0 + tc);
            #pragma unroll
            for (int r = tr; r < 64; r += 16) {
                int4 q = *(const int4*)(qw + (size_t)(k0 + r) * NDIM + n0 + tc);
                tile[r][tc + 0] = (__bf16)((float)q.x * ws.x);
                tile[r][tc + 1] = (__bf16)((float)q.y * ws.y);
                tile[r][tc + 2] = (__bf16)((float)q.z * ws.z);
                tile[r][tc + 3] = (__bf16)((float)q.w * ws.w);
            }
        } else {
            #pragma unroll
            for (int r = tr; r < 64; r += 16) {
                if (r < RANK) {
                    float4 lv = *(const float4*)(lu + (size_t)r * NDIM + n0 + tc);
                    tile[r][tc + 0] = (__bf16)lv.x;
                    tile[r][tc + 1] = (__bf16)lv.y;
                    tile[r][tc + 2] = (__bf16)lv.z;
                    tile[r][tc + 3] = (__bf16)lv.w;
                } else {
                    tile[r][tc + 0] = (__bf16)0.f;
                    tile[r][tc + 1] = (__bf16)0.f;
                    tile[r][tc + 2] = (__bf16)0.f;
                    tile[r][tc + 3] = (__bf16)0.f;
                }
            }
        }
        __syncthreads();
        int nn = tid >> 3;            // 0..31
        int ks = (tid & 7) * 8;       // 0..56
        #pragma unroll
        for (int p = 0; p < 2; ++p) {
            int n = nn + p * 32;
            bf16x8 v;
            #pragma unroll
            for (int e = 0; e < 8; ++e) v[e] = tile[ks + e][n];
            *(bf16x8*)(Wt + (size_t)(n0 + n) * KE + k0 + ks) = v;
        }
        return;
    }

    {
        // ---------------- QUANT role: one row of x ----------------
        int row = b - B_QUANT0;
        const float4* xr4 = (const float4*)(x + (size_t)row * KDIM);
        const float4* sm4 = (const float4*)smooth;
        __bf16* ar = A + (size_t)row * KE;
        #pragma unroll
        for (int p = 0; p < 4; ++p) {
            int i4 = p * 256 + tid;          // float4 index 0..1023
            float4 xv = xr4[i4];
            float4 sv = sm4[i4];
            float4 xs = {xv.x * __builtin_amdgcn_rcpf(sv.x),
                         xv.y * __builtin_amdgcn_rcpf(sv.y),
                         xv.z * __builtin_amdgcn_rcpf(sv.z),
                         xv.w * __builtin_amdgcn_rcpf(sv.w)};
            float a = fmaxf(fmaxf(fabsf(xs.x), fabsf(xs.y)),
                            fmaxf(fabsf(xs.z), fabsf(xs.w)));
            #pragma unroll
            for (int off = 1; off < 16; off <<= 1)
                a = fmaxf(a, __shfl_xor(a, off, 64));  // 16-lane group = 64 elems
            float ascale = fmaxf(a * (1.0f / 7.0f), 1e-8f);
            float rin = __builtin_amdgcn_rcpf(ascale);
            float q0 = fminf(fmaxf(rintf(xs.x * rin), -8.f), 7.f);
            float q1 = fminf(fmaxf(rintf(xs.y * rin), -8.f), 7.f);
            float q2 = fminf(fmaxf(rintf(xs.z * rin), -8.f), 7.f);
            float q3 = fminf(fmaxf(rintf(xs.w * rin), -8.f), 7.f);
            bf16x4 av = {(__bf16)(q0 * ascale), (__bf16)(q1 * ascale),
                         (__bf16)(q2 * ascale), (__bf16)(q3 * ascale)};
            *(bf16x4*)(ar + i4 * 4) = av;
        }
    }
}

// ---------------------------------------------------------------------------
// Reduce split-K partials, write t (bf16) + zero pad into A cols [4096, 4160)
// ---------------------------------------------------------------------------
__global__ __launch_bounds__(256) void k_fin(const float* __restrict__ tws,
                                             __bf16* __restrict__ A) {
    int idx = blockIdx.x * 256 + threadIdx.x;
    int m = idx >> 4, cq = idx & 15;
    int c = cq * 4;
    bf16x4 v = {(__bf16)0.f, (__bf16)0.f, (__bf16)0.f, (__bf16)0.f};
    if (c < RANK) {
        f32x4 s = {0.f, 0.f, 0.f, 0.f};
        #pragma unroll
        for (int sp = 0; sp < NSPLIT; ++sp) {
            f32x4 p = *(const f32x4*)(tws + ((size_t)sp * MDIM + m) * RANK + c);
            s.x += p.x; s.y += p.y; s.z += p.z; s.w += p.w;
        }
        v[0] = (__bf16)s.x; v[1] = (__bf16)s.y; v[2] = (__bf16)s.z; v[3] = (__bf16)s.w;
    }
    *(bf16x4*)(A + (size_t)m * KE + KDIM + c) = v;
}

// ---------------------------------------------------------------------------
// Main GEMM (m97 structure + XOR swizzle). Change this round: non-temporal
// stores for `out` (never re-read) to keep A/Wt resident in L2.
// ---------------------------------------------------------------------------
__global__ __launch_bounds__(256) void k_gemm(const __bf16* __restrict__ A,
                                              const __bf16* __restrict__ Wt,
                                              const float*  __restrict__ bias,
                                              float* __restrict__ out) {
    __shared__ __attribute__((aligned(16))) __bf16 As[128 * 64];
    __shared__ __attribute__((aligned(16))) __bf16 Bs[128 * 64];
    int tid  = threadIdx.x;
    int lane = tid & 63;
    int wave = tid >> 6;
    int quad = lane >> 4;
    int mrow = lane & 15;
    int wm = wave >> 1, wn = wave & 1;
    int m0 = blockIdx.y * 128, n0 = blockIdx.x * 128;

    f32x4 z = {0.f, 0.f, 0.f, 0.f};
    f32x4 acc[4][4];
    #pragma unroll
    for (int i = 0; i < 4; ++i)
        #pragma unroll
        for (int j = 0; j < 4; ++j) acc[i][j] = z;

    const __bf16* Ab = A  + (size_t)m0 * KE;
    const __bf16* Bb = Wt + (size_t)n0 * KE;

    for (int kt = 0; kt < KE / 64; ++kt) {
        int k0 = kt * 64;
        #pragma unroll
        for (int it = 0; it < 4; ++it) {
            int c = it * 256 + tid;       // 16B-slot index 0..1023
            int r = c >> 3;               // tile row 0..127
            int g = (c & 7) ^ (r & 7);    // swizzled col group
            int ldsoff = (it * 256 + wave * 64) * 16;  // wave-uniform base
            __builtin_amdgcn_global_load_lds(GPTR(Ab + (size_t)r * KE + k0 + g * 8),
                                             LPTR((char*)As + ldsoff), 16, 0, 0);
            __builtin_amdgcn_global_load_lds(GPTR(Bb + (size_t)r * KE + k0 + g * 8),
                                             LPTR((char*)Bs + ldsoff), 16, 0, 0);
        }
        __syncthreads();
        #pragma unroll
        for (int s = 0; s < 2; ++s) {
            bf16x8 av[4], bv[4];
            #pragma unroll
            for (int i = 0; i < 4; ++i) {
                int row  = wm * 64 + i * 16 + mrow;
                int slot = row * 8 + ((s * 4 + quad) ^ (row & 7));
                av[i] = *(const bf16x8*)(As + slot * 8);
            }
            #pragma unroll
            for (int j = 0; j < 4; ++j) {
                int row  = wn * 64 + j * 16 + mrow;
                int slot = row * 8 + ((s * 4 + quad) ^ (row & 7));
                bv[j] = *(const bf16x8*)(Bs + slot * 8);
            }
            #pragma unroll
            for (int i = 0; i < 4; ++i)
                #pragma unroll
                for (int j = 0; j < 4; ++j)
                    acc[i][j] = __builtin_amdgcn_mfma_f32_16x16x32_bf16(av[i], bv[j], acc[i][j], 0, 0, 0);
        }
        __syncthreads();
    }

    // epilogue: C/D layout col = lane&15, row = quad*4 + reg (m89/m91)
    #pragma unroll
    for (int j = 0; j < 4; ++j) {
        int col = n0 + wn * 64 + j * 16 + mrow;
        float bvs = bias[col];
        #pragma unroll
        for (int i = 0; i < 4; ++i) {
            int rbase = m0 + wm * 64 + i * 16 + quad * 4;
            #pragma unroll
            for (int r = 0; r < 4; ++r)
                __builtin_nontemporal_store(acc[i][j][r] + bvs,
                                            &out[(size_t)(rbase + r) * NDIM + col]);
        }
    }
}

extern "C" void kernel_launch(void* const* d_in, const int* in_sizes, int n_in,
                              void* d_out, int out_size, void* d_ws, size_t ws_size,
                              hipStream_t stream) {
    const float* x    = (const float*)d_in[0];
    const int*   qw   = (const int*)  d_in[1];
    const float* wsc  = (const float*)d_in[2];
    const float* ld   = (const float*)d_in[3];
    const float* lu   = (const float*)d_in[4];
    const float* sm   = (const float*)d_in[5];
    const float* bias = (const float*)d_in[6];
    float* out = (float*)d_out;

    char* ws = (char*)d_ws;
    __bf16* A   = (__bf16*)ws;                                   // M*KE bf16
    __bf16* Wt  = (__bf16*)(ws + (size_t)MDIM * KE * 2);         // N*KE bf16
    float*  tws = (float*) (ws + (size_t)MDIM * KE * 4);         // NSPLIT*M*RANK f32

    k_prep<<<NBLOCKS, 256, 0, stream>>>(x, qw, wsc, ld, lu, sm, A, Wt, tws);
    k_fin<<<(MDIM * 16) / 256, 256, 0, stream>>>(tws, A);
    k_gemm<<<dim3(NDIM / 128, MDIM / 128), 256, 0, stream>>>(A, Wt, bias, out);
}